// Round 1
// baseline (359.239 us; speedup 1.0000x reference)
//
#include <hip/hip_runtime.h>

#define AS1 __attribute__((address_space(1)))
#define AS3 __attribute__((address_space(3)))

typedef float f32x4 __attribute__((ext_vector_type(4)));
typedef __bf16 bf16x8 __attribute__((ext_vector_type(8)));

__device__ __forceinline__ unsigned short f2bf(float f) {
    union { float f; unsigned u; } v; v.f = f;
    unsigned r = v.u + 0x7fffu + ((v.u >> 16) & 1u);
    return (unsigned short)(r >> 16);
}

// async 16B/lane global->LDS. lds ptr must be wave-uniform; HW adds lane*16.
__device__ __forceinline__ void async16(const void* g, void* l) {
    __builtin_amdgcn_global_load_lds((AS1 void*)g, (AS3 void*)l, 16, 0, 0);
}

// XOR swizzle for 32-col (4-group) rows: 2-way max bank aliasing on ds_read_b128
#define SWZ4(r) ((((r) & 3) ^ (((r) >> 2) & 3)))

// ---------------- weight transpose + bf16 convert: W[K][N] -> Wt[N][K] ----------------
__global__ void transpose_cvt(const float* __restrict__ W, unsigned short* __restrict__ Wt,
                              int K, int N) {
    __shared__ float tile[32][33];
    int n0 = blockIdx.x * 32, k0 = blockIdx.y * 32;
    int tx = threadIdx.x, ty = threadIdx.y;
#pragma unroll
    for (int i = 0; i < 32; i += 8)
        tile[ty + i][tx] = W[(size_t)(k0 + ty + i) * N + n0 + tx];
    __syncthreads();
#pragma unroll
    for (int i = 0; i < 32; i += 8)
        Wt[(size_t)(n0 + ty + i) * K + k0 + tx] = f2bf(tile[tx][ty + i]);
}

// ---------------- LayerNorm (ddof=1, /(std+eps)), fp32 in -> bf16 out ----------------
__global__ __launch_bounds__(256) void ln_kernel(const float* __restrict__ x,
                                                 unsigned short* __restrict__ t,
                                                 const float* __restrict__ alpha,
                                                 const float* __restrict__ bias) {
    const int row = blockIdx.x;
    const float* xr = x + (size_t)row * 768;
    float v[3], sum = 0.f, ss = 0.f;
#pragma unroll
    for (int i = 0; i < 3; i++) {
        v[i] = xr[threadIdx.x + 256 * i];
        sum += v[i]; ss += v[i] * v[i];
    }
#pragma unroll
    for (int off = 32; off; off >>= 1) {
        sum += __shfl_down(sum, off);
        ss  += __shfl_down(ss, off);
    }
    __shared__ float s1[4], s2[4];
    int wid = threadIdx.x >> 6, lane = threadIdx.x & 63;
    if (lane == 0) { s1[wid] = sum; s2[wid] = ss; }
    __syncthreads();
    if (threadIdx.x == 0) {
        float a = 0.f, b = 0.f;
#pragma unroll
        for (int i = 0; i < 4; i++) { a += s1[i]; b += s2[i]; }
        s1[0] = a; s2[0] = b;
    }
    __syncthreads();
    sum = s1[0]; ss = s2[0];
    float mean = sum * (1.f / 768.f);
    float var = (ss - sum * mean) * (1.f / 767.f);   // unbiased (ddof=1)
    float sc = alpha[0] / (sqrtf(fmaxf(var, 0.f)) + 1e-6f);
    float bs = bias[0];
#pragma unroll
    for (int i = 0; i < 3; i++)
        t[(size_t)row * 768 + threadIdx.x + 256 * i] = f2bf(sc * (v[i] - mean) + bs);
}

// ---------------- GEMM: C[M][N] = A[M][K] * Bt[N][K]^T, bf16 in, fp32 acc --------------
// MODE 0: out bf16 = v              MODE 1: out bf16 = relu(v + bias[col])
// MODE 2: out f32 = v + res         MODE 3: out f32 = v + bias[col] + res
template <int MODE>
__global__ __launch_bounds__(256, 2) void gemm_bt(
    const unsigned short* __restrict__ A, const unsigned short* __restrict__ Bt,
    int M, int N, int K, const float* __restrict__ bias,
    const float* __restrict__ res, void* __restrict__ outp) {
    __shared__ __align__(16) unsigned short As[128 * 32];
    __shared__ __align__(16) unsigned short Bs[128 * 32];
    const int tid = threadIdx.x;
    const int lane = tid & 63, w = tid >> 6;
    const int wm = w & 1, wn = w >> 1;
    const int m0 = blockIdx.y * 128, n0 = blockIdx.x * 128;
    const int quad = lane >> 4, l16 = lane & 15;

    // staging: wave w owns chunks 2w,2w+1 of A and of B (1KB each: 64 lanes x 16B)
    const int s0 = (2 * w) * 64 + lane;
    const int r0 = s0 >> 2, g0 = s0 & 3;
    const int s1 = s0 + 64;
    const int r1 = s1 >> 2, g1 = s1 & 3;
    const unsigned short* gA0 = A  + (size_t)(m0 + r0) * K + ((g0 ^ SWZ4(r0)) * 8);
    const unsigned short* gA1 = A  + (size_t)(m0 + r1) * K + ((g1 ^ SWZ4(r1)) * 8);
    const unsigned short* gB0 = Bt + (size_t)(n0 + r0) * K + ((g0 ^ SWZ4(r0)) * 8);
    const unsigned short* gB1 = Bt + (size_t)(n0 + r1) * K + ((g1 ^ SWZ4(r1)) * 8);
    unsigned short* lA0 = As + (2 * w) * 512;
    unsigned short* lA1 = As + (2 * w + 1) * 512;
    unsigned short* lB0 = Bs + (2 * w) * 512;
    unsigned short* lB1 = Bs + (2 * w + 1) * 512;

    f32x4 acc[4][4];
    const f32x4 z = {0.f, 0.f, 0.f, 0.f};
#pragma unroll
    for (int mt = 0; mt < 4; mt++)
#pragma unroll
        for (int nt = 0; nt < 4; nt++) acc[mt][nt] = z;

    const int nK = K >> 5;
    for (int kt = 0; kt < nK; ++kt) {
        __syncthreads();               // previous tile fully consumed
        async16(gA0, lA0); async16(gA1, lA1);
        async16(gB0, lB0); async16(gB1, lB1);
        gA0 += 32; gA1 += 32; gB0 += 32; gB1 += 32;
        __syncthreads();               // staged data visible (vmcnt drained at barrier)
        bf16x8 af[4], bf[4];
#pragma unroll
        for (int mt = 0; mt < 4; mt++) {
            int r = 64 * wm + 16 * mt + l16;
            af[mt] = *(const bf16x8*)&As[r * 32 + ((quad ^ SWZ4(r)) * 8)];
        }
#pragma unroll
        for (int nt = 0; nt < 4; nt++) {
            int r = 64 * wn + 16 * nt + l16;
            bf[nt] = *(const bf16x8*)&Bs[r * 32 + ((quad ^ SWZ4(r)) * 8)];
        }
#pragma unroll
        for (int mt = 0; mt < 4; mt++)
#pragma unroll
            for (int nt = 0; nt < 4; nt++)
                acc[mt][nt] = __builtin_amdgcn_mfma_f32_16x16x32_bf16(af[mt], bf[nt], acc[mt][nt], 0, 0, 0);
    }

#pragma unroll
    for (int mt = 0; mt < 4; mt++) {
#pragma unroll
        for (int nt = 0; nt < 4; nt++) {
            const int col = n0 + 64 * wn + 16 * nt + l16;
            float bv = 0.f;
            if (MODE == 1 || MODE == 3) bv = bias[col];
#pragma unroll
            for (int r = 0; r < 4; r++) {
                const int row = m0 + 64 * wm + 16 * mt + quad * 4 + r;
                const size_t idx = (size_t)row * N + col;
                const float v = acc[mt][nt][r];
                if (MODE == 0) ((unsigned short*)outp)[idx] = f2bf(v);
                else if (MODE == 1) ((unsigned short*)outp)[idx] = f2bf(fmaxf(v + bv, 0.f));
                else if (MODE == 2) ((float*)outp)[idx] = v + res[idx];
                else ((float*)outp)[idx] = v + bv + res[idx];
            }
        }
    }
}

// ---------------- V transpose: qkv[.,1536+h*64+dd] -> vt[bh][dd][S] ----------------
__global__ void v_transpose(const unsigned short* __restrict__ qkvc,
                            unsigned short* __restrict__ vt) {
    __shared__ unsigned short t[64][65];
    const int bh = blockIdx.y, b = bh / 12, h = bh % 12;
    const int s0 = blockIdx.x * 64;
    const int tx = threadIdx.x, ty = threadIdx.y;   // 64 x 4
#pragma unroll
    for (int i = 0; i < 64; i += 4)
        t[ty + i][tx] = qkvc[(size_t)(b * 2048 + s0 + ty + i) * 2304 + 1536 + h * 64 + tx];
    __syncthreads();
#pragma unroll
    for (int i = 0; i < 64; i += 4)
        vt[((size_t)bh * 64 + ty + i) * 2048 + s0 + tx] = t[tx][ty + i];
}

// ---------------- flash attention: 64-row Q tile per block, K-tiles of 128 ------------
__global__ __launch_bounds__(256, 2) void flash_attn(
    const unsigned short* __restrict__ qkvc,   // [4096][2304] fused q|k|v
    const unsigned short* __restrict__ vt,     // [24][64][2048]
    const int* __restrict__ mask,              // [2][2048]
    unsigned short* __restrict__ attno) {      // [4096][768]
    const int bh = blockIdx.y, b = bh / 12, h = bh % 12;
    const int s0 = blockIdx.x * 64;
    __shared__ __align__(16) unsigned short Qs[64 * 64];
    __shared__ __align__(16) unsigned short Ks[128 * 64];
    __shared__ __align__(16) unsigned short Vs[64 * 128];
    __shared__ __align__(16) unsigned short Ps[4][16 * 136];
    __shared__ int Ms[128];
    const int tid = threadIdx.x, lane = tid & 63, w = tid >> 6;
    const int quad = lane >> 4, l16 = lane & 15;

    // stage Q tile [64 rows][64 cols], 8-group rows swizzled with g^(row&7)
    {
        int sl0 = (2 * w) * 64 + lane;
        int r0 = sl0 >> 3, g0 = sl0 & 7;
        int sl1 = sl0 + 64;
        int r1 = sl1 >> 3, g1 = sl1 & 7;
        async16(qkvc + (size_t)(b * 2048 + s0 + r0) * 2304 + h * 64 + ((g0 ^ (r0 & 7)) * 8),
                Qs + (2 * w) * 512);
        async16(qkvc + (size_t)(b * 2048 + s0 + r1) * 2304 + h * 64 + ((g1 ^ (r1 & 7)) * 8),
                Qs + (2 * w + 1) * 512);
    }
    __syncthreads();
    bf16x8 aQ[2];
    {
        int r = 16 * w + l16;
#pragma unroll
        for (int kk = 0; kk < 2; kk++)
            aQ[kk] = *(const bf16x8*)&Qs[r * 64 + (((kk * 4 + quad) ^ (r & 7)) * 8)];
    }

    float mprev[4], lsum[4];
    f32x4 Oacc[4];
    const f32x4 z = {0.f, 0.f, 0.f, 0.f};
#pragma unroll
    for (int r = 0; r < 4; r++) { mprev[r] = -1e30f; lsum[r] = 0.f; }
#pragma unroll
    for (int nt = 0; nt < 4; nt++) Oacc[nt] = z;

    const unsigned short* kbase = qkvc + 768;
    const unsigned short* vbase = vt + (size_t)bh * 64 * 2048;

    for (int j = 0; j < 16; j++) {
        const int k0 = j * 128;
        __syncthreads();   // protect K/V/P LDS from overwrite
        // stage K tile [128][64] (swizzle g^(row&7)), 16 chunks
#pragma unroll
        for (int c = 0; c < 4; c++) {
            int sl = (4 * w + c) * 64 + lane;
            int r = sl >> 3, g = sl & 7;
            async16(kbase + (size_t)(b * 2048 + k0 + r) * 2304 + h * 64 + ((g ^ (r & 7)) * 8),
                    Ks + (4 * w + c) * 512);
        }
        // stage Vt tile [64 dd][128 s] (swizzle g^(row&15)), 16 chunks
#pragma unroll
        for (int c = 0; c < 4; c++) {
            int sl = (4 * w + c) * 64 + lane;
            int r = sl >> 4, g = sl & 15;
            async16(vbase + (size_t)r * 2048 + k0 + ((g ^ (r & 15)) * 8),
                    Vs + (4 * w + c) * 512);
        }
        if (tid < 128) Ms[tid] = mask[b * 2048 + k0 + tid];
        __syncthreads();

        // S = Q K^T for this wave's 16 rows x 128 cols
        f32x4 sc[8];
#pragma unroll
        for (int nt = 0; nt < 8; nt++) {
            sc[nt] = z;
            int rr = nt * 16 + l16;
#pragma unroll
            for (int kk = 0; kk < 2; kk++) {
                bf16x8 bk = *(const bf16x8*)&Ks[rr * 64 + (((kk * 4 + quad) ^ (rr & 7)) * 8)];
                sc[nt] = __builtin_amdgcn_mfma_f32_16x16x32_bf16(aQ[kk], bk, sc[nt], 0, 0, 0);
            }
        }
        // scale, mask quirk, online softmax
        float cmax[4] = {-1e30f, -1e30f, -1e30f, -1e30f};
#pragma unroll
        for (int nt = 0; nt < 8; nt++) {
            const int msk = Ms[nt * 16 + l16];
#pragma unroll
            for (int r = 0; r < 4; r++) {
                float v = sc[nt][r] * 0.125f;
                if (msk == 0) v = 1e-9f;
                sc[nt][r] = v;
                cmax[r] = fmaxf(cmax[r], v);
            }
        }
#pragma unroll
        for (int d = 1; d < 16; d <<= 1)
#pragma unroll
            for (int r = 0; r < 4; r++)
                cmax[r] = fmaxf(cmax[r], __shfl_xor(cmax[r], d, 64));
        float alpha[4], psum[4] = {0.f, 0.f, 0.f, 0.f};
#pragma unroll
        for (int r = 0; r < 4; r++) {
            float mnew = fmaxf(mprev[r], cmax[r]);
            alpha[r] = __expf(mprev[r] - mnew);
            mprev[r] = mnew;
        }
#pragma unroll
        for (int nt = 0; nt < 8; nt++)
#pragma unroll
            for (int r = 0; r < 4; r++) {
                float p = __expf(sc[nt][r] - mprev[r]);
                sc[nt][r] = p;
                psum[r] += p;
            }
#pragma unroll
        for (int d = 1; d < 16; d <<= 1)
#pragma unroll
            for (int r = 0; r < 4; r++)
                psum[r] += __shfl_xor(psum[r], d, 64);
#pragma unroll
        for (int r = 0; r < 4; r++) lsum[r] = lsum[r] * alpha[r] + psum[r];
#pragma unroll
        for (int nt = 0; nt < 4; nt++)
#pragma unroll
            for (int r = 0; r < 4; r++) Oacc[nt][r] *= alpha[r];

        // P: C-layout -> LDS (padded rows, 136 elems) -> A-layout frags
#pragma unroll
        for (int nt = 0; nt < 8; nt++)
#pragma unroll
            for (int r = 0; r < 4; r++)
                Ps[w][(quad * 4 + r) * 136 + nt * 16 + l16] = f2bf(sc[nt][r]);
        __syncthreads();   // make cross-lane P writes safely visible

        // O += P V
#pragma unroll
        for (int ktile = 0; ktile < 4; ktile++) {
            bf16x8 aP = *(const bf16x8*)&Ps[w][l16 * 136 + ktile * 32 + quad * 8];
#pragma unroll
            for (int nt = 0; nt < 4; nt++) {
                int rr = nt * 16 + l16;
                bf16x8 bv = *(const bf16x8*)&Vs[rr * 128 + (((ktile * 4 + quad) ^ (rr & 15)) * 8)];
                Oacc[nt] = __builtin_amdgcn_mfma_f32_16x16x32_bf16(aP, bv, Oacc[nt], 0, 0, 0);
            }
        }
    }

#pragma unroll
    for (int nt = 0; nt < 4; nt++)
#pragma unroll
        for (int r = 0; r < 4; r++) {
            const int row = s0 + 16 * w + quad * 4 + r;
            attno[(size_t)(b * 2048 + row) * 768 + h * 64 + nt * 16 + l16] =
                f2bf(Oacc[nt][r] / lsum[r]);
        }
}

// =====================================================================================
extern "C" void kernel_launch(void* const* d_in, const int* in_sizes, int n_in,
                              void* d_out, int out_size, void* d_ws, size_t ws_size,
                              hipStream_t stream) {
    const float* x    = (const float*)d_in[0];
    const int*   mask = (const int*)d_in[1];
    const float* wq   = (const float*)d_in[2];
    const float* wk   = (const float*)d_in[3];
    const float* wv   = (const float*)d_in[4];
    const float* wo   = (const float*)d_in[5];
    const float* w1   = (const float*)d_in[6];
    const float* b1   = (const float*)d_in[7];
    const float* w2   = (const float*)d_in[8];
    const float* b2   = (const float*)d_in[9];
    const float* ln1a = (const float*)d_in[10];
    const float* ln1b = (const float*)d_in[11];
    const float* ln2a = (const float*)d_in[12];
    const float* ln2b = (const float*)d_in[13];

    char* p = (char*)d_ws;
    auto carve = [&](size_t bytes) {
        char* q = p;
        p += (bytes + 255) & ~(size_t)255;
        return q;
    };
    unsigned short* wTqkv = (unsigned short*)carve((size_t)2304 * 768 * 2);
    unsigned short* wTo   = (unsigned short*)carve((size_t)768 * 768 * 2);
    unsigned short* wT1   = (unsigned short*)carve((size_t)3072 * 768 * 2);
    unsigned short* wT2   = (unsigned short*)carve((size_t)768 * 3072 * 2);
    unsigned short* vtb   = (unsigned short*)carve((size_t)24 * 64 * 2048 * 2);
    float*          x1    = (float*)carve((size_t)4096 * 768 * 4);
    // unionA: [t1 | qkvc] both dead before ffnh is written (sizes match exactly: 24 MB)
    char* unionA = carve((size_t)4096 * 768 * 2 + (size_t)4096 * 2304 * 2);
    unsigned short* t1   = (unsigned short*)unionA;
    unsigned short* qkvc = (unsigned short*)(unionA + (size_t)4096 * 768 * 2);
    unsigned short* ffnh = (unsigned short*)unionA;
    // attno dead after WO gemm; t2 reuses it
    unsigned short* attno = (unsigned short*)carve((size_t)4096 * 768 * 2);
    unsigned short* t2 = attno;

    dim3 tb(32, 8);
    transpose_cvt<<<dim3(24, 24), tb, 0, stream>>>(wq, wTqkv, 768, 768);
    transpose_cvt<<<dim3(24, 24), tb, 0, stream>>>(wk, wTqkv + (size_t)768 * 768, 768, 768);
    transpose_cvt<<<dim3(24, 24), tb, 0, stream>>>(wv, wTqkv + (size_t)1536 * 768, 768, 768);
    transpose_cvt<<<dim3(24, 24), tb, 0, stream>>>(wo, wTo, 768, 768);
    transpose_cvt<<<dim3(96, 24), tb, 0, stream>>>(w1, wT1, 768, 3072);
    transpose_cvt<<<dim3(24, 96), tb, 0, stream>>>(w2, wT2, 3072, 768);

    ln_kernel<<<4096, 256, 0, stream>>>(x, t1, ln1a, ln1b);
    gemm_bt<0><<<dim3(18, 32), 256, 0, stream>>>(t1, wTqkv, 4096, 2304, 768,
                                                 nullptr, nullptr, qkvc);
    v_transpose<<<dim3(32, 24), dim3(64, 4), 0, stream>>>(qkvc, vtb);
    flash_attn<<<dim3(32, 24), 256, 0, stream>>>(qkvc, vtb, mask, attno);
    gemm_bt<2><<<dim3(6, 32), 256, 0, stream>>>(attno, wTo, 4096, 768, 768,
                                                nullptr, x, x1);
    ln_kernel<<<4096, 256, 0, stream>>>(x1, t2, ln2a, ln2b);
    gemm_bt<1><<<dim3(24, 32), 256, 0, stream>>>(t2, wT1, 4096, 3072, 768,
                                                 b1, nullptr, ffnh);
    gemm_bt<3><<<dim3(6, 32), 256, 0, stream>>>(ffnh, wT2, 4096, 768, 3072,
                                                b2, x1, (float*)d_out);
}

// Round 2
// 320.997 us; speedup vs baseline: 1.1191x; 1.1191x over previous
//
#include <hip/hip_runtime.h>

#define AS1 __attribute__((address_space(1)))
#define AS3 __attribute__((address_space(3)))

typedef float f32x4 __attribute__((ext_vector_type(4)));
typedef __bf16 bf16x8 __attribute__((ext_vector_type(8)));

__device__ __forceinline__ unsigned short f2bf(float f) {
    union { float f; unsigned u; } v; v.f = f;
    unsigned r = v.u + 0x7fffu + ((v.u >> 16) & 1u);
    return (unsigned short)(r >> 16);
}

// async 16B/lane global->LDS. lds ptr must be wave-uniform; HW adds lane*16.
__device__ __forceinline__ void async16(const void* g, void* l) {
    __builtin_amdgcn_global_load_lds((AS1 void*)g, (AS3 void*)l, 16, 0, 0);
}

// XOR swizzle for 32-col (4-group) rows: 2-way max bank aliasing on ds_read_b128
#define SWZ4(r) ((((r) & 3) ^ (((r) >> 2) & 3)))

// ---------------- weight transpose + bf16 convert: W[K][N] -> Wt[N][K] ----------------
__global__ void transpose_cvt(const float* __restrict__ W, unsigned short* __restrict__ Wt,
                              int K, int N) {
    __shared__ float tile[32][33];
    int n0 = blockIdx.x * 32, k0 = blockIdx.y * 32;
    int tx = threadIdx.x, ty = threadIdx.y;
#pragma unroll
    for (int i = 0; i < 32; i += 8)
        tile[ty + i][tx] = W[(size_t)(k0 + ty + i) * N + n0 + tx];
    __syncthreads();
#pragma unroll
    for (int i = 0; i < 32; i += 8)
        Wt[(size_t)(n0 + ty + i) * K + k0 + tx] = f2bf(tile[tx][ty + i]);
}

// ---------------- LayerNorm (ddof=1, /(std+eps)), fp32 in -> bf16 out ----------------
__global__ __launch_bounds__(256) void ln_kernel(const float* __restrict__ x,
                                                 unsigned short* __restrict__ t,
                                                 const float* __restrict__ alpha,
                                                 const float* __restrict__ bias) {
    const int row = blockIdx.x;
    const float* xr = x + (size_t)row * 768;
    float v[3], sum = 0.f, ss = 0.f;
#pragma unroll
    for (int i = 0; i < 3; i++) {
        v[i] = xr[threadIdx.x + 256 * i];
        sum += v[i]; ss += v[i] * v[i];
    }
#pragma unroll
    for (int off = 32; off; off >>= 1) {
        sum += __shfl_down(sum, off);
        ss  += __shfl_down(ss, off);
    }
    __shared__ float s1[4], s2[4];
    int wid = threadIdx.x >> 6, lane = threadIdx.x & 63;
    if (lane == 0) { s1[wid] = sum; s2[wid] = ss; }
    __syncthreads();
    if (threadIdx.x == 0) {
        float a = 0.f, b = 0.f;
#pragma unroll
        for (int i = 0; i < 4; i++) { a += s1[i]; b += s2[i]; }
        s1[0] = a; s2[0] = b;
    }
    __syncthreads();
    sum = s1[0]; ss = s2[0];
    float mean = sum * (1.f / 768.f);
    float var = (ss - sum * mean) * (1.f / 767.f);   // unbiased (ddof=1)
    float sc = alpha[0] / (sqrtf(fmaxf(var, 0.f)) + 1e-6f);
    float bs = bias[0];
#pragma unroll
    for (int i = 0; i < 3; i++)
        t[(size_t)row * 768 + threadIdx.x + 256 * i] = f2bf(sc * (v[i] - mean) + bs);
}

// ---------------- GEMM: C[M][N] = A[M][K] * Bt[N][K]^T, bf16 in, fp32 acc --------------
// MODE 0: out bf16 = v              MODE 1: out bf16 = relu(v + bias[col])
// MODE 2: out f32 = v + res         MODE 3: out f32 = v + bias[col] + res
template <int MODE>
__global__ __launch_bounds__(256, 2) void gemm_bt(
    const unsigned short* __restrict__ A, const unsigned short* __restrict__ Bt,
    int M, int N, int K, const float* __restrict__ bias,
    const float* __restrict__ res, void* __restrict__ outp) {
    __shared__ __align__(16) unsigned short As[128 * 32];
    __shared__ __align__(16) unsigned short Bs[128 * 32];
    const int tid = threadIdx.x;
    const int lane = tid & 63, w = tid >> 6;
    const int wm = w & 1, wn = w >> 1;
    const int m0 = blockIdx.y * 128, n0 = blockIdx.x * 128;
    const int quad = lane >> 4, l16 = lane & 15;

    // staging: wave w owns chunks 2w,2w+1 of A and of B (1KB each: 64 lanes x 16B)
    const int s0 = (2 * w) * 64 + lane;
    const int r0 = s0 >> 2, g0 = s0 & 3;
    const int s1 = s0 + 64;
    const int r1 = s1 >> 2, g1 = s1 & 3;
    const unsigned short* gA0 = A  + (size_t)(m0 + r0) * K + ((g0 ^ SWZ4(r0)) * 8);
    const unsigned short* gA1 = A  + (size_t)(m0 + r1) * K + ((g1 ^ SWZ4(r1)) * 8);
    const unsigned short* gB0 = Bt + (size_t)(n0 + r0) * K + ((g0 ^ SWZ4(r0)) * 8);
    const unsigned short* gB1 = Bt + (size_t)(n0 + r1) * K + ((g1 ^ SWZ4(r1)) * 8);
    unsigned short* lA0 = As + (2 * w) * 512;
    unsigned short* lA1 = As + (2 * w + 1) * 512;
    unsigned short* lB0 = Bs + (2 * w) * 512;
    unsigned short* lB1 = Bs + (2 * w + 1) * 512;

    f32x4 acc[4][4];
    const f32x4 z = {0.f, 0.f, 0.f, 0.f};
#pragma unroll
    for (int mt = 0; mt < 4; mt++)
#pragma unroll
        for (int nt = 0; nt < 4; nt++) acc[mt][nt] = z;

    const int nK = K >> 5;
    for (int kt = 0; kt < nK; ++kt) {
        __syncthreads();               // previous tile fully consumed
        async16(gA0, lA0); async16(gA1, lA1);
        async16(gB0, lB0); async16(gB1, lB1);
        gA0 += 32; gA1 += 32; gB0 += 32; gB1 += 32;
        __syncthreads();               // staged data visible (vmcnt drained at barrier)
        bf16x8 af[4], bf[4];
#pragma unroll
        for (int mt = 0; mt < 4; mt++) {
            int r = 64 * wm + 16 * mt + l16;
            af[mt] = *(const bf16x8*)&As[r * 32 + ((quad ^ SWZ4(r)) * 8)];
        }
#pragma unroll
        for (int nt = 0; nt < 4; nt++) {
            int r = 64 * wn + 16 * nt + l16;
            bf[nt] = *(const bf16x8*)&Bs[r * 32 + ((quad ^ SWZ4(r)) * 8)];
        }
#pragma unroll
        for (int mt = 0; mt < 4; mt++)
#pragma unroll
            for (int nt = 0; nt < 4; nt++)
                acc[mt][nt] = __builtin_amdgcn_mfma_f32_16x16x32_bf16(af[mt], bf[nt], acc[mt][nt], 0, 0, 0);
    }

#pragma unroll
    for (int mt = 0; mt < 4; mt++) {
#pragma unroll
        for (int nt = 0; nt < 4; nt++) {
            const int col = n0 + 64 * wn + 16 * nt + l16;
            float bv = 0.f;
            if (MODE == 1 || MODE == 3) bv = bias[col];
#pragma unroll
            for (int r = 0; r < 4; r++) {
                const int row = m0 + 64 * wm + 16 * mt + quad * 4 + r;
                const size_t idx = (size_t)row * N + col;
                const float v = acc[mt][nt][r];
                if (MODE == 0) ((unsigned short*)outp)[idx] = f2bf(v);
                else if (MODE == 1) ((unsigned short*)outp)[idx] = f2bf(fmaxf(v + bv, 0.f));
                else if (MODE == 2) ((float*)outp)[idx] = v + res[idx];
                else ((float*)outp)[idx] = v + bv + res[idx];
            }
        }
    }
}

// ---------------- V transpose: qkv[.,1536+h*64+dd] -> vt[bh][dd][S] ----------------
__global__ void v_transpose(const unsigned short* __restrict__ qkvc,
                            unsigned short* __restrict__ vt) {
    __shared__ unsigned short t[64][65];
    const int bh = blockIdx.y, b = bh / 12, h = bh % 12;
    const int s0 = blockIdx.x * 64;
    const int tx = threadIdx.x, ty = threadIdx.y;   // 64 x 4
#pragma unroll
    for (int i = 0; i < 64; i += 4)
        t[ty + i][tx] = qkvc[(size_t)(b * 2048 + s0 + ty + i) * 2304 + 1536 + h * 64 + tx];
    __syncthreads();
#pragma unroll
    for (int i = 0; i < 64; i += 4)
        vt[((size_t)bh * 64 + ty + i) * 2048 + s0 + tx] = t[tx][ty + i];
}

// ---------------- flash attention v2 ------------------------------------------------
// Changes vs v1: no online max (scores bounded; softmax is shift-invariant, exp direct),
// row-sum via ones-column MFMA instead of shuffle tree, exp2 with folded constant,
// Ps unioned with dead Qs region (LDS 58.9K -> 49.5K => 3 blocks/CU; grid 768 = 256x3
// fully resident), wave-local Ps (no barrier for the C->A P round-trip).
__global__ __launch_bounds__(256, 3) void flash_attn(
    const unsigned short* __restrict__ qkvc,   // [4096][2304] fused q|k|v
    const unsigned short* __restrict__ vt,     // [24][64][2048]
    const int* __restrict__ mask,              // [2][2048]
    unsigned short* __restrict__ attno) {      // [4096][768]
    const int bh = blockIdx.y, b = bh / 12, h = bh % 12;
    const int s0 = blockIdx.x * 64;
    // UQP: Qs[64*64] (used only before the loop) unioned with Ps[4][16*136]
    __shared__ __align__(16) unsigned short UQP[4 * 16 * 136];
    __shared__ __align__(16) unsigned short Ks[128 * 64];
    __shared__ __align__(16) unsigned short Vs[64 * 128];
    __shared__ int Ms[128];
    const int tid = threadIdx.x, lane = tid & 63, w = tid >> 6;
    const int quad = lane >> 4, l16 = lane & 15;

    // stage Q tile [64 rows][64 cols], 8-group rows swizzled with g^(row&7)
    {
        int sl0 = (2 * w) * 64 + lane;
        int r0 = sl0 >> 3, g0 = sl0 & 7;
        int sl1 = sl0 + 64;
        int r1 = sl1 >> 3, g1 = sl1 & 7;
        async16(qkvc + (size_t)(b * 2048 + s0 + r0) * 2304 + h * 64 + ((g0 ^ (r0 & 7)) * 8),
                UQP + (2 * w) * 512);
        async16(qkvc + (size_t)(b * 2048 + s0 + r1) * 2304 + h * 64 + ((g1 ^ (r1 & 7)) * 8),
                UQP + (2 * w + 1) * 512);
    }
    __syncthreads();
    bf16x8 aQ[2];
    {
        int r = 16 * w + l16;
#pragma unroll
        for (int kk = 0; kk < 2; kk++)
            aQ[kk] = *(const bf16x8*)&UQP[r * 64 + (((kk * 4 + quad) ^ (r & 7)) * 8)];
    }
    // NOTE: all waves' aQ reads complete before the first j-loop barrier (each wave
    // drains lgkmcnt before s_barrier), so Ps may overwrite the Qs region after it.
    __bf16* Ps = (__bf16*)(UQP + w * (16 * 136));

    f32x4 Oacc[4], Lacc;
    const f32x4 z = {0.f, 0.f, 0.f, 0.f};
#pragma unroll
    for (int nt = 0; nt < 4; nt++) Oacc[nt] = z;
    Lacc = z;
    bf16x8 ones;
#pragma unroll
    for (int i = 0; i < 8; i++) ones[i] = (__bf16)1.0f;

    const unsigned short* kbase = qkvc + 768;
    const unsigned short* vbase = vt + (size_t)bh * 64 * 2048;
    const float SCL = 0.125f * 1.44269504088896340736f;   // 1/sqrt(64) * log2(e)
    const float MSK = 1.4426950408889634e-9f;             // 1e-9 * log2(e)

    for (int j = 0; j < 16; j++) {
        const int k0 = j * 128;
        __syncthreads();   // all waves done reading K/V of previous tile
        // stage K tile [128][64] (swizzle g^(row&7)), 16 chunks
#pragma unroll
        for (int c = 0; c < 4; c++) {
            int sl = (4 * w + c) * 64 + lane;
            int r = sl >> 3, g = sl & 7;
            async16(kbase + (size_t)(b * 2048 + k0 + r) * 2304 + h * 64 + ((g ^ (r & 7)) * 8),
                    Ks + (4 * w + c) * 512);
        }
        // stage Vt tile [64 dd][128 s] (swizzle g^(row&15)), 16 chunks
#pragma unroll
        for (int c = 0; c < 4; c++) {
            int sl = (4 * w + c) * 64 + lane;
            int r = sl >> 4, g = sl & 15;
            async16(vbase + (size_t)r * 2048 + k0 + ((g ^ (r & 15)) * 8),
                    Vs + (4 * w + c) * 512);
        }
        if (tid < 128) Ms[tid] = mask[b * 2048 + k0 + tid];
        __syncthreads();

        // S = Q K^T for this wave's 16 rows x 128 cols
        f32x4 sc[8];
#pragma unroll
        for (int nt = 0; nt < 8; nt++) {
            int rr = nt * 16 + l16;
            bf16x8 bk0 = *(const bf16x8*)&Ks[rr * 64 + (((0 + quad) ^ (rr & 7)) * 8)];
            bf16x8 bk1 = *(const bf16x8*)&Ks[rr * 64 + (((4 + quad) ^ (rr & 7)) * 8)];
            sc[nt] = __builtin_amdgcn_mfma_f32_16x16x32_bf16(aQ[0], bk0, z, 0, 0, 0);
            sc[nt] = __builtin_amdgcn_mfma_f32_16x16x32_bf16(aQ[1], bk1, sc[nt], 0, 0, 0);
        }
        // p = exp(s/8) with the mask quirk (masked: s := 1e-9). No max subtraction:
        // softmax is shift-invariant and |s/8| is small; exp2 with folded log2(e).
#pragma unroll
        for (int nt = 0; nt < 8; nt++) {
            const int msk = Ms[nt * 16 + l16];
#pragma unroll
            for (int r = 0; r < 4; r++) {
                float v = msk ? sc[nt][r] * SCL : MSK;
                sc[nt][r] = __builtin_amdgcn_exp2f(v);
            }
        }
        // P: C-layout -> wave-local LDS (stride 136 keeps rows 16B-aligned) -> A-frags
#pragma unroll
        for (int nt = 0; nt < 8; nt++)
#pragma unroll
            for (int r = 0; r < 4; r++)
                Ps[(quad * 4 + r) * 136 + nt * 16 + l16] = (__bf16)sc[nt][r];
        // no barrier: Ps is wave-local; compiler orders the ds ops via lgkmcnt

        // O += P V ; L += P 1  (row-sums via ones-column MFMA, lands in every lane)
#pragma unroll
        for (int ktile = 0; ktile < 4; ktile++) {
            bf16x8 aP = *(const bf16x8*)&Ps[l16 * 136 + ktile * 32 + quad * 8];
            Lacc = __builtin_amdgcn_mfma_f32_16x16x32_bf16(aP, ones, Lacc, 0, 0, 0);
#pragma unroll
            for (int nt = 0; nt < 4; nt++) {
                int rr = nt * 16 + l16;
                bf16x8 bv = *(const bf16x8*)&Vs[rr * 128 + (((ktile * 4 + quad) ^ (rr & 15)) * 8)];
                Oacc[nt] = __builtin_amdgcn_mfma_f32_16x16x32_bf16(aP, bv, Oacc[nt], 0, 0, 0);
            }
        }
    }

    float inv[4];
#pragma unroll
    for (int r = 0; r < 4; r++) inv[r] = 1.0f / Lacc[r];
#pragma unroll
    for (int nt = 0; nt < 4; nt++)
#pragma unroll
        for (int r = 0; r < 4; r++) {
            const int row = s0 + 16 * w + quad * 4 + r;
            attno[(size_t)(b * 2048 + row) * 768 + h * 64 + nt * 16 + l16] =
                f2bf(Oacc[nt][r] * inv[r]);
        }
}

// =====================================================================================
extern "C" void kernel_launch(void* const* d_in, const int* in_sizes, int n_in,
                              void* d_out, int out_size, void* d_ws, size_t ws_size,
                              hipStream_t stream) {
    const float* x    = (const float*)d_in[0];
    const int*   mask = (const int*)d_in[1];
    const float* wq   = (const float*)d_in[2];
    const float* wk   = (const float*)d_in[3];
    const float* wv   = (const float*)d_in[4];
    const float* wo   = (const float*)d_in[5];
    const float* w1   = (const float*)d_in[6];
    const float* b1   = (const float*)d_in[7];
    const float* w2   = (const float*)d_in[8];
    const float* b2   = (const float*)d_in[9];
    const float* ln1a = (const float*)d_in[10];
    const float* ln1b = (const float*)d_in[11];
    const float* ln2a = (const float*)d_in[12];
    const float* ln2b = (const float*)d_in[13];

    char* p = (char*)d_ws;
    auto carve = [&](size_t bytes) {
        char* q = p;
        p += (bytes + 255) & ~(size_t)255;
        return q;
    };
    unsigned short* wTqkv = (unsigned short*)carve((size_t)2304 * 768 * 2);
    unsigned short* wTo   = (unsigned short*)carve((size_t)768 * 768 * 2);
    unsigned short* wT1   = (unsigned short*)carve((size_t)3072 * 768 * 2);
    unsigned short* wT2   = (unsigned short*)carve((size_t)768 * 3072 * 2);
    unsigned short* vtb   = (unsigned short*)carve((size_t)24 * 64 * 2048 * 2);
    float*          x1    = (float*)carve((size_t)4096 * 768 * 4);
    // unionA: [t1 | qkvc] both dead before ffnh is written (sizes match exactly: 24 MB)
    char* unionA = carve((size_t)4096 * 768 * 2 + (size_t)4096 * 2304 * 2);
    unsigned short* t1   = (unsigned short*)unionA;
    unsigned short* qkvc = (unsigned short*)(unionA + (size_t)4096 * 768 * 2);
    unsigned short* ffnh = (unsigned short*)unionA;
    // attno dead after WO gemm; t2 reuses it
    unsigned short* attno = (unsigned short*)carve((size_t)4096 * 768 * 2);
    unsigned short* t2 = attno;

    dim3 tb(32, 8);
    transpose_cvt<<<dim3(24, 24), tb, 0, stream>>>(wq, wTqkv, 768, 768);
    transpose_cvt<<<dim3(24, 24), tb, 0, stream>>>(wk, wTqkv + (size_t)768 * 768, 768, 768);
    transpose_cvt<<<dim3(24, 24), tb, 0, stream>>>(wv, wTqkv + (size_t)1536 * 768, 768, 768);
    transpose_cvt<<<dim3(24, 24), tb, 0, stream>>>(wo, wTo, 768, 768);
    transpose_cvt<<<dim3(96, 24), tb, 0, stream>>>(w1, wT1, 768, 3072);
    transpose_cvt<<<dim3(24, 96), tb, 0, stream>>>(w2, wT2, 3072, 768);

    ln_kernel<<<4096, 256, 0, stream>>>(x, t1, ln1a, ln1b);
    gemm_bt<0><<<dim3(18, 32), 256, 0, stream>>>(t1, wTqkv, 4096, 2304, 768,
                                                 nullptr, nullptr, qkvc);
    v_transpose<<<dim3(32, 24), dim3(64, 4), 0, stream>>>(qkvc, vtb);
    flash_attn<<<dim3(32, 24), 256, 0, stream>>>(qkvc, vtb, mask, attno);
    gemm_bt<2><<<dim3(6, 32), 256, 0, stream>>>(attno, wTo, 4096, 768, 768,
                                                nullptr, x, x1);
    ln_kernel<<<4096, 256, 0, stream>>>(x1, t2, ln2a, ln2b);
    gemm_bt<1><<<dim3(24, 32), 256, 0, stream>>>(t2, wT1, 4096, 3072, 768,
                                                 b1, nullptr, ffnh);
    gemm_bt<3><<<dim3(6, 32), 256, 0, stream>>>(ffnh, wT2, 4096, 768, 3072,
                                                b2, x1, (float*)d_out);
}

// Round 3
// 306.901 us; speedup vs baseline: 1.1705x; 1.0459x over previous
//
#include <hip/hip_runtime.h>

#define AS1 __attribute__((address_space(1)))
#define AS3 __attribute__((address_space(3)))

typedef float f32x4 __attribute__((ext_vector_type(4)));
typedef __bf16 bf16x8 __attribute__((ext_vector_type(8)));

__device__ __forceinline__ unsigned short f2bf(float f) {
    union { float f; unsigned u; } v; v.f = f;
    unsigned r = v.u + 0x7fffu + ((v.u >> 16) & 1u);
    return (unsigned short)(r >> 16);
}

// async 16B/lane global->LDS. lds ptr must be wave-uniform; HW adds lane*16.
__device__ __forceinline__ void async16(const void* g, void* l) {
    __builtin_amdgcn_global_load_lds((AS1 void*)g, (AS3 void*)l, 16, 0, 0);
}

// XOR swizzle for 32-col (4-group) rows: 2-way max bank aliasing on ds_read_b128
#define SWZ4(r) ((((r) & 3) ^ (((r) >> 2) & 3)))

// ---------------- weight transpose + bf16 convert: W[K][N] -> Wt[N][K] ----------------
__global__ void transpose_cvt(const float* __restrict__ W, unsigned short* __restrict__ Wt,
                              int K, int N) {
    __shared__ float tile[32][33];
    int n0 = blockIdx.x * 32, k0 = blockIdx.y * 32;
    int tx = threadIdx.x, ty = threadIdx.y;
#pragma unroll
    for (int i = 0; i < 32; i += 8)
        tile[ty + i][tx] = W[(size_t)(k0 + ty + i) * N + n0 + tx];
    __syncthreads();
#pragma unroll
    for (int i = 0; i < 32; i += 8)
        Wt[(size_t)(n0 + ty + i) * K + k0 + tx] = f2bf(tile[tx][ty + i]);
}

// ---------------- LayerNorm (ddof=1, /(std+eps)), fp32 in -> bf16 out ----------------
__global__ __launch_bounds__(256) void ln_kernel(const float* __restrict__ x,
                                                 unsigned short* __restrict__ t,
                                                 const float* __restrict__ alpha,
                                                 const float* __restrict__ bias) {
    const int row = blockIdx.x;
    const float* xr = x + (size_t)row * 768;
    float v[3], sum = 0.f, ss = 0.f;
#pragma unroll
    for (int i = 0; i < 3; i++) {
        v[i] = xr[threadIdx.x + 256 * i];
        sum += v[i]; ss += v[i] * v[i];
    }
#pragma unroll
    for (int off = 32; off; off >>= 1) {
        sum += __shfl_down(sum, off);
        ss  += __shfl_down(ss, off);
    }
    __shared__ float s1[4], s2[4];
    int wid = threadIdx.x >> 6, lane = threadIdx.x & 63;
    if (lane == 0) { s1[wid] = sum; s2[wid] = ss; }
    __syncthreads();
    if (threadIdx.x == 0) {
        float a = 0.f, b = 0.f;
#pragma unroll
        for (int i = 0; i < 4; i++) { a += s1[i]; b += s2[i]; }
        s1[0] = a; s2[0] = b;
    }
    __syncthreads();
    sum = s1[0]; ss = s2[0];
    float mean = sum * (1.f / 768.f);
    float var = (ss - sum * mean) * (1.f / 767.f);   // unbiased (ddof=1)
    float sc = alpha[0] / (sqrtf(fmaxf(var, 0.f)) + 1e-6f);
    float bs = bias[0];
#pragma unroll
    for (int i = 0; i < 3; i++)
        t[(size_t)row * 768 + threadIdx.x + 256 * i] = f2bf(sc * (v[i] - mean) + bs);
}

// ---------------- GEMM 128x128: C[M][N] = A[M][K] * Bt[N][K]^T, bf16 in, fp32 acc ------
// MODE 0: out bf16 = v              MODE 1: out bf16 = relu(v + bias[col])
// MODE 2: out f32 = v + res         MODE 3: out f32 = v + bias[col] + res
template <int MODE>
__global__ __launch_bounds__(256, 2) void gemm_bt(
    const unsigned short* __restrict__ A, const unsigned short* __restrict__ Bt,
    int M, int N, int K, const float* __restrict__ bias,
    const float* __restrict__ res, void* __restrict__ outp) {
    __shared__ __align__(16) unsigned short As[128 * 32];
    __shared__ __align__(16) unsigned short Bs[128 * 32];
    const int tid = threadIdx.x;
    const int lane = tid & 63, w = tid >> 6;
    const int wm = w & 1, wn = w >> 1;
    const int m0 = blockIdx.y * 128, n0 = blockIdx.x * 128;
    const int quad = lane >> 4, l16 = lane & 15;

    // staging: wave w owns chunks 2w,2w+1 of A and of B (1KB each: 64 lanes x 16B)
    const int s0 = (2 * w) * 64 + lane;
    const int r0 = s0 >> 2, g0 = s0 & 3;
    const int s1 = s0 + 64;
    const int r1 = s1 >> 2, g1 = s1 & 3;
    const unsigned short* gA0 = A  + (size_t)(m0 + r0) * K + ((g0 ^ SWZ4(r0)) * 8);
    const unsigned short* gA1 = A  + (size_t)(m0 + r1) * K + ((g1 ^ SWZ4(r1)) * 8);
    const unsigned short* gB0 = Bt + (size_t)(n0 + r0) * K + ((g0 ^ SWZ4(r0)) * 8);
    const unsigned short* gB1 = Bt + (size_t)(n0 + r1) * K + ((g1 ^ SWZ4(r1)) * 8);
    unsigned short* lA0 = As + (2 * w) * 512;
    unsigned short* lA1 = As + (2 * w + 1) * 512;
    unsigned short* lB0 = Bs + (2 * w) * 512;
    unsigned short* lB1 = Bs + (2 * w + 1) * 512;

    f32x4 acc[4][4];
    const f32x4 z = {0.f, 0.f, 0.f, 0.f};
#pragma unroll
    for (int mt = 0; mt < 4; mt++)
#pragma unroll
        for (int nt = 0; nt < 4; nt++) acc[mt][nt] = z;

    const int nK = K >> 5;
    for (int kt = 0; kt < nK; ++kt) {
        __syncthreads();               // previous tile fully consumed
        async16(gA0, lA0); async16(gA1, lA1);
        async16(gB0, lB0); async16(gB1, lB1);
        gA0 += 32; gA1 += 32; gB0 += 32; gB1 += 32;
        __syncthreads();               // staged data visible (vmcnt drained at barrier)
        bf16x8 af[4], bf[4];
#pragma unroll
        for (int mt = 0; mt < 4; mt++) {
            int r = 64 * wm + 16 * mt + l16;
            af[mt] = *(const bf16x8*)&As[r * 32 + ((quad ^ SWZ4(r)) * 8)];
        }
#pragma unroll
        for (int nt = 0; nt < 4; nt++) {
            int r = 64 * wn + 16 * nt + l16;
            bf[nt] = *(const bf16x8*)&Bs[r * 32 + ((quad ^ SWZ4(r)) * 8)];
        }
#pragma unroll
        for (int mt = 0; mt < 4; mt++)
#pragma unroll
            for (int nt = 0; nt < 4; nt++)
                acc[mt][nt] = __builtin_amdgcn_mfma_f32_16x16x32_bf16(af[mt], bf[nt], acc[mt][nt], 0, 0, 0);
    }

#pragma unroll
    for (int mt = 0; mt < 4; mt++) {
#pragma unroll
        for (int nt = 0; nt < 4; nt++) {
            const int col = n0 + 64 * wn + 16 * nt + l16;
            float bv = 0.f;
            if (MODE == 1 || MODE == 3) bv = bias[col];
#pragma unroll
            for (int r = 0; r < 4; r++) {
                const int row = m0 + 64 * wm + 16 * mt + quad * 4 + r;
                const size_t idx = (size_t)row * N + col;
                const float v = acc[mt][nt][r];
                if (MODE == 0) ((unsigned short*)outp)[idx] = f2bf(v);
                else if (MODE == 1) ((unsigned short*)outp)[idx] = f2bf(fmaxf(v + bv, 0.f));
                else if (MODE == 2) ((float*)outp)[idx] = v + res[idx];
                else ((float*)outp)[idx] = v + bv + res[idx];
            }
        }
    }
}

// ---------------- GEMM 64x64 tile: for skinny-N GEMMs (WO, FFN2) ----------------------
// Same math as gemm_bt but 64x64 tile -> 4x the blocks (768 for M=4096,N=768) so the
// m97-style K-loop gets 3 blocks/CU of wave-level overlap instead of <=1 block/CU.
// Wave w owns a 16-row m-strip x full 64 cols (1 af frag, 4 bf frags, 4 MFMA/iter).
template <int MODE>
__global__ __launch_bounds__(256, 3) void gemm64_bt(
    const unsigned short* __restrict__ A, const unsigned short* __restrict__ Bt,
    int M, int N, int K, const float* __restrict__ bias,
    const float* __restrict__ res, void* __restrict__ outp) {
    __shared__ __align__(16) unsigned short As[64 * 32];
    __shared__ __align__(16) unsigned short Bs[64 * 32];
    const int tid = threadIdx.x;
    const int lane = tid & 63, w = tid >> 6;
    const int m0 = blockIdx.y * 64, n0 = blockIdx.x * 64;
    const int quad = lane >> 4, l16 = lane & 15;

    // staging: 4 chunks each for A and B; wave w takes chunk w of each
    const int sl = w * 64 + lane;
    const int r = sl >> 2, g = sl & 3;
    const unsigned short* gA = A  + (size_t)(m0 + r) * K + ((g ^ SWZ4(r)) * 8);
    const unsigned short* gB = Bt + (size_t)(n0 + r) * K + ((g ^ SWZ4(r)) * 8);
    unsigned short* lA = As + w * 512;
    unsigned short* lB = Bs + w * 512;

    f32x4 acc[4];
    const f32x4 z = {0.f, 0.f, 0.f, 0.f};
#pragma unroll
    for (int nt = 0; nt < 4; nt++) acc[nt] = z;

    const int nK = K >> 5;
    for (int kt = 0; kt < nK; ++kt) {
        __syncthreads();
        async16(gA, lA); async16(gB, lB);
        gA += 32; gB += 32;
        __syncthreads();
        const int ra = 16 * w + l16;
        bf16x8 af = *(const bf16x8*)&As[ra * 32 + ((quad ^ SWZ4(ra)) * 8)];
#pragma unroll
        for (int nt = 0; nt < 4; nt++) {
            int rb = 16 * nt + l16;
            bf16x8 bf = *(const bf16x8*)&Bs[rb * 32 + ((quad ^ SWZ4(rb)) * 8)];
            acc[nt] = __builtin_amdgcn_mfma_f32_16x16x32_bf16(af, bf, acc[nt], 0, 0, 0);
        }
    }

#pragma unroll
    for (int nt = 0; nt < 4; nt++) {
        const int col = n0 + 16 * nt + l16;
        float bv = 0.f;
        if (MODE == 1 || MODE == 3) bv = bias[col];
#pragma unroll
        for (int rr = 0; rr < 4; rr++) {
            const int row = m0 + 16 * w + quad * 4 + rr;
            const size_t idx = (size_t)row * N + col;
            const float v = acc[nt][rr];
            if (MODE == 0) ((unsigned short*)outp)[idx] = f2bf(v);
            else if (MODE == 1) ((unsigned short*)outp)[idx] = f2bf(fmaxf(v + bv, 0.f));
            else if (MODE == 2) ((float*)outp)[idx] = v + res[idx];
            else ((float*)outp)[idx] = v + bv + res[idx];
        }
    }
}

// ---------------- V transpose: qkv[.,1536+h*64+dd] -> vt[bh][dd][S] ----------------
__global__ void v_transpose(const unsigned short* __restrict__ qkvc,
                            unsigned short* __restrict__ vt) {
    __shared__ unsigned short t[64][65];
    const int bh = blockIdx.y, b = bh / 12, h = bh % 12;
    const int s0 = blockIdx.x * 64;
    const int tx = threadIdx.x, ty = threadIdx.y;   // 64 x 4
#pragma unroll
    for (int i = 0; i < 64; i += 4)
        t[ty + i][tx] = qkvc[(size_t)(b * 2048 + s0 + ty + i) * 2304 + 1536 + h * 64 + tx];
    __syncthreads();
#pragma unroll
    for (int i = 0; i < 64; i += 4)
        vt[((size_t)bh * 64 + ty + i) * 2048 + s0 + tx] = t[tx][ty + i];
}

// ---------------- flash attention v2 ------------------------------------------------
__global__ __launch_bounds__(256, 3) void flash_attn(
    const unsigned short* __restrict__ qkvc,   // [4096][2304] fused q|k|v
    const unsigned short* __restrict__ vt,     // [24][64][2048]
    const int* __restrict__ mask,              // [2][2048]
    unsigned short* __restrict__ attno) {      // [4096][768]
    const int bh = blockIdx.y, b = bh / 12, h = bh % 12;
    const int s0 = blockIdx.x * 64;
    // UQP: Qs[64*64] (used only before the loop) unioned with Ps[4][16*136]
    __shared__ __align__(16) unsigned short UQP[4 * 16 * 136];
    __shared__ __align__(16) unsigned short Ks[128 * 64];
    __shared__ __align__(16) unsigned short Vs[64 * 128];
    __shared__ int Ms[128];
    const int tid = threadIdx.x, lane = tid & 63, w = tid >> 6;
    const int quad = lane >> 4, l16 = lane & 15;

    // stage Q tile [64 rows][64 cols], 8-group rows swizzled with g^(row&7)
    {
        int sl0 = (2 * w) * 64 + lane;
        int r0 = sl0 >> 3, g0 = sl0 & 7;
        int sl1 = sl0 + 64;
        int r1 = sl1 >> 3, g1 = sl1 & 7;
        async16(qkvc + (size_t)(b * 2048 + s0 + r0) * 2304 + h * 64 + ((g0 ^ (r0 & 7)) * 8),
                UQP + (2 * w) * 512);
        async16(qkvc + (size_t)(b * 2048 + s0 + r1) * 2304 + h * 64 + ((g1 ^ (r1 & 7)) * 8),
                UQP + (2 * w + 1) * 512);
    }
    __syncthreads();
    bf16x8 aQ[2];
    {
        int r = 16 * w + l16;
#pragma unroll
        for (int kk = 0; kk < 2; kk++)
            aQ[kk] = *(const bf16x8*)&UQP[r * 64 + (((kk * 4 + quad) ^ (r & 7)) * 8)];
    }
    __bf16* Ps = (__bf16*)(UQP + w * (16 * 136));

    f32x4 Oacc[4], Lacc;
    const f32x4 z = {0.f, 0.f, 0.f, 0.f};
#pragma unroll
    for (int nt = 0; nt < 4; nt++) Oacc[nt] = z;
    Lacc = z;
    bf16x8 ones;
#pragma unroll
    for (int i = 0; i < 8; i++) ones[i] = (__bf16)1.0f;

    const unsigned short* kbase = qkvc + 768;
    const unsigned short* vbase = vt + (size_t)bh * 64 * 2048;
    const float SCL = 0.125f * 1.44269504088896340736f;   // 1/sqrt(64) * log2(e)
    const float MSK = 1.4426950408889634e-9f;             // 1e-9 * log2(e)

    for (int j = 0; j < 16; j++) {
        const int k0 = j * 128;
        __syncthreads();   // all waves done reading K/V of previous tile
#pragma unroll
        for (int c = 0; c < 4; c++) {
            int sl = (4 * w + c) * 64 + lane;
            int r = sl >> 3, g = sl & 7;
            async16(kbase + (size_t)(b * 2048 + k0 + r) * 2304 + h * 64 + ((g ^ (r & 7)) * 8),
                    Ks + (4 * w + c) * 512);
        }
#pragma unroll
        for (int c = 0; c < 4; c++) {
            int sl = (4 * w + c) * 64 + lane;
            int r = sl >> 4, g = sl & 15;
            async16(vbase + (size_t)r * 2048 + k0 + ((g ^ (r & 15)) * 8),
                    Vs + (4 * w + c) * 512);
        }
        if (tid < 128) Ms[tid] = mask[b * 2048 + k0 + tid];
        __syncthreads();

        // S = Q K^T for this wave's 16 rows x 128 cols
        f32x4 sc[8];
#pragma unroll
        for (int nt = 0; nt < 8; nt++) {
            int rr = nt * 16 + l16;
            bf16x8 bk0 = *(const bf16x8*)&Ks[rr * 64 + (((0 + quad) ^ (rr & 7)) * 8)];
            bf16x8 bk1 = *(const bf16x8*)&Ks[rr * 64 + (((4 + quad) ^ (rr & 7)) * 8)];
            sc[nt] = __builtin_amdgcn_mfma_f32_16x16x32_bf16(aQ[0], bk0, z, 0, 0, 0);
            sc[nt] = __builtin_amdgcn_mfma_f32_16x16x32_bf16(aQ[1], bk1, sc[nt], 0, 0, 0);
        }
        // p = exp(s/8) with the mask quirk; no max subtraction (scores bounded)
#pragma unroll
        for (int nt = 0; nt < 8; nt++) {
            const int msk = Ms[nt * 16 + l16];
#pragma unroll
            for (int r = 0; r < 4; r++) {
                float v = msk ? sc[nt][r] * SCL : MSK;
                sc[nt][r] = __builtin_amdgcn_exp2f(v);
            }
        }
        // P: C-layout -> wave-local LDS -> A-frags
#pragma unroll
        for (int nt = 0; nt < 8; nt++)
#pragma unroll
            for (int r = 0; r < 4; r++)
                Ps[(quad * 4 + r) * 136 + nt * 16 + l16] = (__bf16)sc[nt][r];

        // O += P V ; L += P 1
#pragma unroll
        for (int ktile = 0; ktile < 4; ktile++) {
            bf16x8 aP = *(const bf16x8*)&Ps[l16 * 136 + ktile * 32 + quad * 8];
            Lacc = __builtin_amdgcn_mfma_f32_16x16x32_bf16(aP, ones, Lacc, 0, 0, 0);
#pragma unroll
            for (int nt = 0; nt < 4; nt++) {
                int rr = nt * 16 + l16;
                bf16x8 bv = *(const bf16x8*)&Vs[rr * 128 + (((ktile * 4 + quad) ^ (rr & 15)) * 8)];
                Oacc[nt] = __builtin_amdgcn_mfma_f32_16x16x32_bf16(aP, bv, Oacc[nt], 0, 0, 0);
            }
        }
    }

    float inv[4];
#pragma unroll
    for (int r = 0; r < 4; r++) inv[r] = 1.0f / Lacc[r];
#pragma unroll
    for (int nt = 0; nt < 4; nt++)
#pragma unroll
        for (int r = 0; r < 4; r++) {
            const int row = s0 + 16 * w + quad * 4 + r;
            attno[(size_t)(b * 2048 + row) * 768 + h * 64 + nt * 16 + l16] =
                f2bf(Oacc[nt][r] * inv[r]);
        }
}

// =====================================================================================
extern "C" void kernel_launch(void* const* d_in, const int* in_sizes, int n_in,
                              void* d_out, int out_size, void* d_ws, size_t ws_size,
                              hipStream_t stream) {
    const float* x    = (const float*)d_in[0];
    const int*   mask = (const int*)d_in[1];
    const float* wq   = (const float*)d_in[2];
    const float* wk   = (const float*)d_in[3];
    const float* wv   = (const float*)d_in[4];
    const float* wo   = (const float*)d_in[5];
    const float* w1   = (const float*)d_in[6];
    const float* b1   = (const float*)d_in[7];
    const float* w2   = (const float*)d_in[8];
    const float* b2   = (const float*)d_in[9];
    const float* ln1a = (const float*)d_in[10];
    const float* ln1b = (const float*)d_in[11];
    const float* ln2a = (const float*)d_in[12];
    const float* ln2b = (const float*)d_in[13];

    char* p = (char*)d_ws;
    auto carve = [&](size_t bytes) {
        char* q = p;
        p += (bytes + 255) & ~(size_t)255;
        return q;
    };
    unsigned short* wTqkv = (unsigned short*)carve((size_t)2304 * 768 * 2);
    unsigned short* wTo   = (unsigned short*)carve((size_t)768 * 768 * 2);
    unsigned short* wT1   = (unsigned short*)carve((size_t)3072 * 768 * 2);
    unsigned short* wT2   = (unsigned short*)carve((size_t)768 * 3072 * 2);
    unsigned short* vtb   = (unsigned short*)carve((size_t)24 * 64 * 2048 * 2);
    float*          x1    = (float*)carve((size_t)4096 * 768 * 4);
    // unionA: [t1 | qkvc] both dead before ffnh is written (sizes match exactly: 24 MB)
    char* unionA = carve((size_t)4096 * 768 * 2 + (size_t)4096 * 2304 * 2);
    unsigned short* t1   = (unsigned short*)unionA;
    unsigned short* qkvc = (unsigned short*)(unionA + (size_t)4096 * 768 * 2);
    unsigned short* ffnh = (unsigned short*)unionA;
    // attno dead after WO gemm; t2 reuses it
    unsigned short* attno = (unsigned short*)carve((size_t)4096 * 768 * 2);
    unsigned short* t2 = attno;

    dim3 tb(32, 8);
    transpose_cvt<<<dim3(24, 24), tb, 0, stream>>>(wq, wTqkv, 768, 768);
    transpose_cvt<<<dim3(24, 24), tb, 0, stream>>>(wk, wTqkv + (size_t)768 * 768, 768, 768);
    transpose_cvt<<<dim3(24, 24), tb, 0, stream>>>(wv, wTqkv + (size_t)1536 * 768, 768, 768);
    transpose_cvt<<<dim3(24, 24), tb, 0, stream>>>(wo, wTo, 768, 768);
    transpose_cvt<<<dim3(96, 24), tb, 0, stream>>>(w1, wT1, 768, 3072);
    transpose_cvt<<<dim3(24, 96), tb, 0, stream>>>(w2, wT2, 3072, 768);

    ln_kernel<<<4096, 256, 0, stream>>>(x, t1, ln1a, ln1b);
    gemm_bt<0><<<dim3(18, 32), 256, 0, stream>>>(t1, wTqkv, 4096, 2304, 768,
                                                 nullptr, nullptr, qkvc);
    v_transpose<<<dim3(32, 24), dim3(64, 4), 0, stream>>>(qkvc, vtb);
    flash_attn<<<dim3(32, 24), 256, 0, stream>>>(qkvc, vtb, mask, attno);
    // N=768 GEMMs: 64x64 tiles -> 768 blocks (3/CU) instead of 192 (<1/CU)
    gemm64_bt<2><<<dim3(12, 64), 256, 0, stream>>>(attno, wTo, 4096, 768, 768,
                                                   nullptr, x, x1);
    ln_kernel<<<4096, 256, 0, stream>>>(x1, t2, ln2a, ln2b);
    gemm_bt<1><<<dim3(24, 32), 256, 0, stream>>>(t2, wT1, 4096, 3072, 768,
                                                 b1, nullptr, ffnh);
    gemm64_bt<3><<<dim3(12, 64), 256, 0, stream>>>(ffnh, wT2, 4096, 768, 3072,
                                                   b2, x1, (float*)d_out);
}

// Round 4
// 280.106 us; speedup vs baseline: 1.2825x; 1.0957x over previous
//
#include <hip/hip_runtime.h>

typedef float f32x4 __attribute__((ext_vector_type(4)));
typedef __bf16 bf16x8 __attribute__((ext_vector_type(8)));

__device__ __forceinline__ unsigned short f2bf(float f) {
    union { float f; unsigned u; } v; v.f = f;
    unsigned r = v.u + 0x7fffu + ((v.u >> 16) & 1u);
    return (unsigned short)(r >> 16);
}

#define AS1 __attribute__((address_space(1)))
#define AS3 __attribute__((address_space(3)))
// async 16B/lane global->LDS (flash kernel only)
__device__ __forceinline__ void async16(const void* g, void* l) {
    __builtin_amdgcn_global_load_lds((AS1 void*)g, (AS3 void*)l, 16, 0, 0);
}

// CK-style barrier: orders LDS only (lgkmcnt), leaves global loads (vmcnt) in flight.
// This is what lets the register-prefetch pipeline keep loads live across the barrier.
__device__ __forceinline__ void sync_lds() {
    asm volatile("s_waitcnt lgkmcnt(0)\n\ts_barrier" ::: "memory");
}

// XOR swizzle for 32-col (4-group) rows
#define SWZ4(r) ((((r) & 3) ^ (((r) >> 2) & 3)))

// ---------------- weight transpose + bf16 convert: W[K][N] -> Wt[N][K] ----------------
__global__ void transpose_cvt(const float* __restrict__ W, unsigned short* __restrict__ Wt,
                              int K, int N) {
    __shared__ float tile[32][33];
    int n0 = blockIdx.x * 32, k0 = blockIdx.y * 32;
    int tx = threadIdx.x, ty = threadIdx.y;
#pragma unroll
    for (int i = 0; i < 32; i += 8)
        tile[ty + i][tx] = W[(size_t)(k0 + ty + i) * N + n0 + tx];
    __syncthreads();
#pragma unroll
    for (int i = 0; i < 32; i += 8)
        Wt[(size_t)(n0 + ty + i) * K + k0 + tx] = f2bf(tile[tx][ty + i]);
}

// ---------------- LayerNorm (ddof=1, /(std+eps)), fp32 in -> bf16 out ----------------
__global__ __launch_bounds__(256) void ln_kernel(const float* __restrict__ x,
                                                 unsigned short* __restrict__ t,
                                                 const float* __restrict__ alpha,
                                                 const float* __restrict__ bias) {
    const int row = blockIdx.x;
    const float* xr = x + (size_t)row * 768;
    float v[3], sum = 0.f, ss = 0.f;
#pragma unroll
    for (int i = 0; i < 3; i++) {
        v[i] = xr[threadIdx.x + 256 * i];
        sum += v[i]; ss += v[i] * v[i];
    }
#pragma unroll
    for (int off = 32; off; off >>= 1) {
        sum += __shfl_down(sum, off);
        ss  += __shfl_down(ss, off);
    }
    __shared__ float s1[4], s2[4];
    int wid = threadIdx.x >> 6, lane = threadIdx.x & 63;
    if (lane == 0) { s1[wid] = sum; s2[wid] = ss; }
    __syncthreads();
    if (threadIdx.x == 0) {
        float a = 0.f, b = 0.f;
#pragma unroll
        for (int i = 0; i < 4; i++) { a += s1[i]; b += s2[i]; }
        s1[0] = a; s2[0] = b;
    }
    __syncthreads();
    sum = s1[0]; ss = s2[0];
    float mean = sum * (1.f / 768.f);
    float var = (ss - sum * mean) * (1.f / 767.f);   // unbiased (ddof=1)
    float sc = alpha[0] / (sqrtf(fmaxf(var, 0.f)) + 1e-6f);
    float bs = bias[0];
#pragma unroll
    for (int i = 0; i < 3; i++)
        t[(size_t)row * 768 + threadIdx.x + 256 * i] = f2bf(sc * (v[i] - mean) + bs);
}

// ---------------- GEMM 128x128, register-prefetch pipelined, BK=32 --------------------
// MODE 0: out bf16 = v              MODE 1: out bf16 = relu(v + bias[col])
// MODE 2: out f32 = v + res         MODE 3: out f32 = v + bias[col] + res
// K-loop per iter: ds_write staged tile -> prefetch next tile to VGPRs -> sync_lds
// (lgkm only; prefetch stays in flight) -> ds_read frags + 16 MFMA. One barrier/iter.
template <int MODE>
__global__ __launch_bounds__(256, 3) void gemm_bt(
    const unsigned short* __restrict__ A, const unsigned short* __restrict__ Bt,
    int M, int N, int K, const float* __restrict__ bias,
    const float* __restrict__ res, void* __restrict__ outp) {
    __shared__ __align__(16) unsigned short As[2][128 * 32];
    __shared__ __align__(16) unsigned short Bs[2][128 * 32];
    const int tid = threadIdx.x;
    const int lane = tid & 63, w = tid >> 6;
    const int wm = w & 1, wn = w >> 1;
    const int m0 = blockIdx.y * 128, n0 = blockIdx.x * 128;
    const int quad = lane >> 4, l16 = lane & 15;

    // staging: 512 16B-units per matrix per tile; thread owns units tid, tid+256
    const int r0 = tid >> 2, g0 = tid & 3;           // rows 0..63
    const int r1 = r0 + 64, g1 = g0;                 // rows 64..127
    const unsigned short* gA0 = A  + (size_t)(m0 + r0) * K + g0 * 8;
    const unsigned short* gA1 = A  + (size_t)(m0 + r1) * K + g1 * 8;
    const unsigned short* gB0 = Bt + (size_t)(n0 + r0) * K + g0 * 8;
    const unsigned short* gB1 = Bt + (size_t)(n0 + r1) * K + g1 * 8;
    const int wA0 = r0 * 32 + ((g0 ^ SWZ4(r0)) * 8);
    const int wA1 = r1 * 32 + ((g1 ^ SWZ4(r1)) * 8);

    f32x4 acc[4][4];
    const f32x4 z = {0.f, 0.f, 0.f, 0.f};
#pragma unroll
    for (int mt = 0; mt < 4; mt++)
#pragma unroll
        for (int nt = 0; nt < 4; nt++) acc[mt][nt] = z;

    // prologue: prefetch tile 0
    bf16x8 ra0 = *(const bf16x8*)gA0, ra1 = *(const bf16x8*)gA1;
    bf16x8 rb0 = *(const bf16x8*)gB0, rb1 = *(const bf16x8*)gB1;
    gA0 += 32; gA1 += 32; gB0 += 32; gB1 += 32;

    const int nK = K >> 5;
    for (int kt = 0; kt < nK; ++kt) {
        unsigned short* Ac = As[kt & 1];
        unsigned short* Bc = Bs[kt & 1];
        *(bf16x8*)&Ac[wA0] = ra0; *(bf16x8*)&Ac[wA1] = ra1;
        *(bf16x8*)&Bc[wA0] = rb0; *(bf16x8*)&Bc[wA1] = rb1;
        if (kt + 1 < nK) {
            ra0 = *(const bf16x8*)gA0; ra1 = *(const bf16x8*)gA1;
            rb0 = *(const bf16x8*)gB0; rb1 = *(const bf16x8*)gB1;
            gA0 += 32; gA1 += 32; gB0 += 32; gB1 += 32;
        }
        sync_lds();
        bf16x8 af[4], bf[4];
#pragma unroll
        for (int mt = 0; mt < 4; mt++) {
            int r = 64 * wm + 16 * mt + l16;
            af[mt] = *(const bf16x8*)&Ac[r * 32 + ((quad ^ SWZ4(r)) * 8)];
        }
#pragma unroll
        for (int nt = 0; nt < 4; nt++) {
            int r = 64 * wn + 16 * nt + l16;
            bf[nt] = *(const bf16x8*)&Bc[r * 32 + ((quad ^ SWZ4(r)) * 8)];
        }
#pragma unroll
        for (int mt = 0; mt < 4; mt++)
#pragma unroll
            for (int nt = 0; nt < 4; nt++)
                acc[mt][nt] = __builtin_amdgcn_mfma_f32_16x16x32_bf16(af[mt], bf[nt], acc[mt][nt], 0, 0, 0);
    }

#pragma unroll
    for (int mt = 0; mt < 4; mt++) {
#pragma unroll
        for (int nt = 0; nt < 4; nt++) {
            const int col = n0 + 64 * wn + 16 * nt + l16;
            float bv = 0.f;
            if (MODE == 1 || MODE == 3) bv = bias[col];
#pragma unroll
            for (int r = 0; r < 4; r++) {
                const int row = m0 + 64 * wm + 16 * mt + quad * 4 + r;
                const size_t idx = (size_t)row * N + col;
                const float v = acc[mt][nt][r];
                if (MODE == 0) ((unsigned short*)outp)[idx] = f2bf(v);
                else if (MODE == 1) ((unsigned short*)outp)[idx] = f2bf(fmaxf(v + bv, 0.f));
                else if (MODE == 2) ((float*)outp)[idx] = v + res[idx];
                else ((float*)outp)[idx] = v + bv + res[idx];
            }
        }
    }
}

// ---------------- GEMM 64x64, register-prefetch pipelined, BK=64 ----------------------
// For skinny-N GEMMs (WO, FFN2): 768 blocks (3/CU). BK=64 -> 8 MFMA/wave/iter and
// half the barriers of BK=32. Rows are 64 elems = 8 groups, swizzle g^(r&7).
template <int MODE>
__global__ __launch_bounds__(256, 3) void gemm64_bt(
    const unsigned short* __restrict__ A, const unsigned short* __restrict__ Bt,
    int M, int N, int K, const float* __restrict__ bias,
    const float* __restrict__ res, void* __restrict__ outp) {
    __shared__ __align__(16) unsigned short As[2][64 * 64];
    __shared__ __align__(16) unsigned short Bs[2][64 * 64];
    const int tid = threadIdx.x;
    const int lane = tid & 63, w = tid >> 6;
    const int m0 = blockIdx.y * 64, n0 = blockIdx.x * 64;
    const int quad = lane >> 4, l16 = lane & 15;

    // staging: 512 16B-units per matrix per tile (64 rows x 8 groups)
    const int r0 = tid >> 3, g0 = tid & 7;           // rows 0..31
    const int r1 = r0 + 32, g1 = g0;                 // rows 32..63
    const unsigned short* gA0 = A  + (size_t)(m0 + r0) * K + g0 * 8;
    const unsigned short* gA1 = A  + (size_t)(m0 + r1) * K + g1 * 8;
    const unsigned short* gB0 = Bt + (size_t)(n0 + r0) * K + g0 * 8;
    const unsigned short* gB1 = Bt + (size_t)(n0 + r1) * K + g1 * 8;
    const int wA0 = r0 * 64 + ((g0 ^ (r0 & 7)) * 8);
    const int wA1 = r1 * 64 + ((g1 ^ (r1 & 7)) * 8);

    f32x4 acc[4];
    const f32x4 z = {0.f, 0.f, 0.f, 0.f};
#pragma unroll
    for (int nt = 0; nt < 4; nt++) acc[nt] = z;

    bf16x8 ra0 = *(const bf16x8*)gA0, ra1 = *(const bf16x8*)gA1;
    bf16x8 rb0 = *(const bf16x8*)gB0, rb1 = *(const bf16x8*)gB1;
    gA0 += 64; gA1 += 64; gB0 += 64; gB1 += 64;

    const int nK = K >> 6;
    for (int kt = 0; kt < nK; ++kt) {
        unsigned short* Ac = As[kt & 1];
        unsigned short* Bc = Bs[kt & 1];
        *(bf16x8*)&Ac[wA0] = ra0; *(bf16x8*)&Ac[wA1] = ra1;
        *(bf16x8*)&Bc[wA0] = rb0; *(bf16x8*)&Bc[wA1] = rb1;
        if (kt + 1 < nK) {
            ra0 = *(const bf16x8*)gA0; ra1 = *(const bf16x8*)gA1;
            rb0 = *(const bf16x8*)gB0; rb1 = *(const bf16x8*)gB1;
            gA0 += 64; gA1 += 64; gB0 += 64; gB1 += 64;
        }
        sync_lds();
        const int ra = 16 * w + l16;
        bf16x8 af0 = *(const bf16x8*)&Ac[ra * 64 + (((0 + quad) ^ (ra & 7)) * 8)];
        bf16x8 af1 = *(const bf16x8*)&Ac[ra * 64 + (((4 + quad) ^ (ra & 7)) * 8)];
#pragma unroll
        for (int nt = 0; nt < 4; nt++) {
            int rb = 16 * nt + l16;
            bf16x8 bf0 = *(const bf16x8*)&Bc[rb * 64 + (((0 + quad) ^ (rb & 7)) * 8)];
            bf16x8 bf1 = *(const bf16x8*)&Bc[rb * 64 + (((4 + quad) ^ (rb & 7)) * 8)];
            acc[nt] = __builtin_amdgcn_mfma_f32_16x16x32_bf16(af0, bf0, acc[nt], 0, 0, 0);
            acc[nt] = __builtin_amdgcn_mfma_f32_16x16x32_bf16(af1, bf1, acc[nt], 0, 0, 0);
        }
    }

#pragma unroll
    for (int nt = 0; nt < 4; nt++) {
        const int col = n0 + 16 * nt + l16;
        float bv = 0.f;
        if (MODE == 1 || MODE == 3) bv = bias[col];
#pragma unroll
        for (int rr = 0; rr < 4; rr++) {
            const int row = m0 + 16 * w + quad * 4 + rr;
            const size_t idx = (size_t)row * N + col;
            const float v = acc[nt][rr];
            if (MODE == 0) ((unsigned short*)outp)[idx] = f2bf(v);
            else if (MODE == 1) ((unsigned short*)outp)[idx] = f2bf(fmaxf(v + bv, 0.f));
            else if (MODE == 2) ((float*)outp)[idx] = v + res[idx];
            else ((float*)outp)[idx] = v + bv + res[idx];
        }
    }
}

// ---------------- V transpose: qkv[.,1536+h*64+dd] -> vt[bh][dd][S] ----------------
__global__ void v_transpose(const unsigned short* __restrict__ qkvc,
                            unsigned short* __restrict__ vt) {
    __shared__ unsigned short t[64][65];
    const int bh = blockIdx.y, b = bh / 12, h = bh % 12;
    const int s0 = blockIdx.x * 64;
    const int tx = threadIdx.x, ty = threadIdx.y;   // 64 x 4
#pragma unroll
    for (int i = 0; i < 64; i += 4)
        t[ty + i][tx] = qkvc[(size_t)(b * 2048 + s0 + ty + i) * 2304 + 1536 + h * 64 + tx];
    __syncthreads();
#pragma unroll
    for (int i = 0; i < 64; i += 4)
        vt[((size_t)bh * 64 + ty + i) * 2048 + s0 + tx] = t[tx][ty + i];
}

// ---------------- flash attention v2 ------------------------------------------------
__global__ __launch_bounds__(256, 3) void flash_attn(
    const unsigned short* __restrict__ qkvc,   // [4096][2304] fused q|k|v
    const unsigned short* __restrict__ vt,     // [24][64][2048]
    const int* __restrict__ mask,              // [2][2048]
    unsigned short* __restrict__ attno) {      // [4096][768]
    const int bh = blockIdx.y, b = bh / 12, h = bh % 12;
    const int s0 = blockIdx.x * 64;
    __shared__ __align__(16) unsigned short UQP[4 * 16 * 136];
    __shared__ __align__(16) unsigned short Ks[128 * 64];
    __shared__ __align__(16) unsigned short Vs[64 * 128];
    __shared__ int Ms[128];
    const int tid = threadIdx.x, lane = tid & 63, w = tid >> 6;
    const int quad = lane >> 4, l16 = lane & 15;

    {
        int sl0 = (2 * w) * 64 + lane;
        int r0 = sl0 >> 3, g0 = sl0 & 7;
        int sl1 = sl0 + 64;
        int r1 = sl1 >> 3, g1 = sl1 & 7;
        async16(qkvc + (size_t)(b * 2048 + s0 + r0) * 2304 + h * 64 + ((g0 ^ (r0 & 7)) * 8),
                UQP + (2 * w) * 512);
        async16(qkvc + (size_t)(b * 2048 + s0 + r1) * 2304 + h * 64 + ((g1 ^ (r1 & 7)) * 8),
                UQP + (2 * w + 1) * 512);
    }
    __syncthreads();
    bf16x8 aQ[2];
    {
        int r = 16 * w + l16;
#pragma unroll
        for (int kk = 0; kk < 2; kk++)
            aQ[kk] = *(const bf16x8*)&UQP[r * 64 + (((kk * 4 + quad) ^ (r & 7)) * 8)];
    }
    __bf16* Ps = (__bf16*)(UQP + w * (16 * 136));

    f32x4 Oacc[4], Lacc;
    const f32x4 z = {0.f, 0.f, 0.f, 0.f};
#pragma unroll
    for (int nt = 0; nt < 4; nt++) Oacc[nt] = z;
    Lacc = z;
    bf16x8 ones;
#pragma unroll
    for (int i = 0; i < 8; i++) ones[i] = (__bf16)1.0f;

    const unsigned short* kbase = qkvc + 768;
    const unsigned short* vbase = vt + (size_t)bh * 64 * 2048;
    const float SCL = 0.125f * 1.44269504088896340736f;   // 1/sqrt(64) * log2(e)
    const float MSK = 1.4426950408889634e-9f;             // 1e-9 * log2(e)

    for (int j = 0; j < 16; j++) {
        const int k0 = j * 128;
        __syncthreads();
#pragma unroll
        for (int c = 0; c < 4; c++) {
            int sl = (4 * w + c) * 64 + lane;
            int r = sl >> 3, g = sl & 7;
            async16(kbase + (size_t)(b * 2048 + k0 + r) * 2304 + h * 64 + ((g ^ (r & 7)) * 8),
                    Ks + (4 * w + c) * 512);
        }
#pragma unroll
        for (int c = 0; c < 4; c++) {
            int sl = (4 * w + c) * 64 + lane;
            int r = sl >> 4, g = sl & 15;
            async16(vbase + (size_t)r * 2048 + k0 + ((g ^ (r & 15)) * 8),
                    Vs + (4 * w + c) * 512);
        }
        if (tid < 128) Ms[tid] = mask[b * 2048 + k0 + tid];
        __syncthreads();

        f32x4 sc[8];
#pragma unroll
        for (int nt = 0; nt < 8; nt++) {
            int rr = nt * 16 + l16;
            bf16x8 bk0 = *(const bf16x8*)&Ks[rr * 64 + (((0 + quad) ^ (rr & 7)) * 8)];
            bf16x8 bk1 = *(const bf16x8*)&Ks[rr * 64 + (((4 + quad) ^ (rr & 7)) * 8)];
            sc[nt] = __builtin_amdgcn_mfma_f32_16x16x32_bf16(aQ[0], bk0, z, 0, 0, 0);
            sc[nt] = __builtin_amdgcn_mfma_f32_16x16x32_bf16(aQ[1], bk1, sc[nt], 0, 0, 0);
        }
#pragma unroll
        for (int nt = 0; nt < 8; nt++) {
            const int msk = Ms[nt * 16 + l16];
#pragma unroll
            for (int r = 0; r < 4; r++) {
                float v = msk ? sc[nt][r] * SCL : MSK;
                sc[nt][r] = __builtin_amdgcn_exp2f(v);
            }
        }
#pragma unroll
        for (int nt = 0; nt < 8; nt++)
#pragma unroll
            for (int r = 0; r < 4; r++)
                Ps[(quad * 4 + r) * 136 + nt * 16 + l16] = (__bf16)sc[nt][r];

#pragma unroll
        for (int ktile = 0; ktile < 4; ktile++) {
            bf16x8 aP = *(const bf16x8*)&Ps[l16 * 136 + ktile * 32 + quad * 8];
            Lacc = __builtin_amdgcn_mfma_f32_16x16x32_bf16(aP, ones, Lacc, 0, 0, 0);
#pragma unroll
            for (int nt = 0; nt < 4; nt++) {
                int rr = nt * 16 + l16;
                bf16x8 bv = *(const bf16x8*)&Vs[rr * 128 + (((ktile * 4 + quad) ^ (rr & 15)) * 8)];
                Oacc[nt] = __builtin_amdgcn_mfma_f32_16x16x32_bf16(aP, bv, Oacc[nt], 0, 0, 0);
            }
        }
    }

    float inv[4];
#pragma unroll
    for (int r = 0; r < 4; r++) inv[r] = 1.0f / Lacc[r];
#pragma unroll
    for (int nt = 0; nt < 4; nt++)
#pragma unroll
        for (int r = 0; r < 4; r++) {
            const int row = s0 + 16 * w + quad * 4 + r;
            attno[(size_t)(b * 2048 + row) * 768 + h * 64 + nt * 16 + l16] =
                f2bf(Oacc[nt][r] * inv[r]);
        }
}

// =====================================================================================
extern "C" void kernel_launch(void* const* d_in, const int* in_sizes, int n_in,
                              void* d_out, int out_size, void* d_ws, size_t ws_size,
                              hipStream_t stream) {
    const float* x    = (const float*)d_in[0];
    const int*   mask = (const int*)d_in[1];
    const float* wq   = (const float*)d_in[2];
    const float* wk   = (const float*)d_in[3];
    const float* wv   = (const float*)d_in[4];
    const float* wo   = (const float*)d_in[5];
    const float* w1   = (const float*)d_in[6];
    const float* b1   = (const float*)d_in[7];
    const float* w2   = (const float*)d_in[8];
    const float* b2   = (const float*)d_in[9];
    const float* ln1a = (const float*)d_in[10];
    const float* ln1b = (const float*)d_in[11];
    const float* ln2a = (const float*)d_in[12];
    const float* ln2b = (const float*)d_in[13];

    char* p = (char*)d_ws;
    auto carve = [&](size_t bytes) {
        char* q = p;
        p += (bytes + 255) & ~(size_t)255;
        return q;
    };
    unsigned short* wTqkv = (unsigned short*)carve((size_t)2304 * 768 * 2);
    unsigned short* wTo   = (unsigned short*)carve((size_t)768 * 768 * 2);
    unsigned short* wT1   = (unsigned short*)carve((size_t)3072 * 768 * 2);
    unsigned short* wT2   = (unsigned short*)carve((size_t)768 * 3072 * 2);
    unsigned short* vtb   = (unsigned short*)carve((size_t)24 * 64 * 2048 * 2);
    float*          x1    = (float*)carve((size_t)4096 * 768 * 4);
    char* unionA = carve((size_t)4096 * 768 * 2 + (size_t)4096 * 2304 * 2);
    unsigned short* t1   = (unsigned short*)unionA;
    unsigned short* qkvc = (unsigned short*)(unionA + (size_t)4096 * 768 * 2);
    unsigned short* ffnh = (unsigned short*)unionA;
    unsigned short* attno = (unsigned short*)carve((size_t)4096 * 768 * 2);
    unsigned short* t2 = attno;

    dim3 tb(32, 8);
    transpose_cvt<<<dim3(24, 24), tb, 0, stream>>>(wq, wTqkv, 768, 768);
    transpose_cvt<<<dim3(24, 24), tb, 0, stream>>>(wk, wTqkv + (size_t)768 * 768, 768, 768);
    transpose_cvt<<<dim3(24, 24), tb, 0, stream>>>(wv, wTqkv + (size_t)1536 * 768, 768, 768);
    transpose_cvt<<<dim3(24, 24), tb, 0, stream>>>(wo, wTo, 768, 768);
    transpose_cvt<<<dim3(96, 24), tb, 0, stream>>>(w1, wT1, 768, 3072);
    transpose_cvt<<<dim3(24, 96), tb, 0, stream>>>(w2, wT2, 3072, 768);

    ln_kernel<<<4096, 256, 0, stream>>>(x, t1, ln1a, ln1b);
    gemm_bt<0><<<dim3(18, 32), 256, 0, stream>>>(t1, wTqkv, 4096, 2304, 768,
                                                 nullptr, nullptr, qkvc);
    v_transpose<<<dim3(32, 24), dim3(64, 4), 0, stream>>>(qkvc, vtb);
    flash_attn<<<dim3(32, 24), 256, 0, stream>>>(qkvc, vtb, mask, attno);
    gemm64_bt<2><<<dim3(12, 64), 256, 0, stream>>>(attno, wTo, 4096, 768, 768,
                                                   nullptr, x, x1);
    ln_kernel<<<4096, 256, 0, stream>>>(x1, t2, ln2a, ln2b);
    gemm_bt<1><<<dim3(24, 32), 256, 0, stream>>>(t2, wT1, 4096, 3072, 768,
                                                 b1, nullptr, ffnh);
    gemm64_bt<3><<<dim3(12, 64), 256, 0, stream>>>(ffnh, wT2, 4096, 768, 3072,
                                                   b2, x1, (float*)d_out);
}